// Round 2
// baseline (190.335 us; speedup 1.0000x reference)
//
#include <hip/hip_runtime.h>

#define HID 256
#define LK  2048
#define LQ  64
#define BSZ 8
#define M   16
#define NKEY (BSZ * M)   // 128

// ---------------------------------------------------------------------------
// Kernel 1:
//  blocks [0, BSZ): per-batch query column-sum + projection to u[b]
//        u[b][h] = sum_o (W_q qs[b] + Lq b_q)[o] * w_k[o][h]
//  blocks [BSZ, BSZ + NKEY*split): key chunk column sums -> partial[kb][256]
//  Query blocks first so the uniform key blocks form the dispatch tail.
// ---------------------------------------------------------------------------
__global__ void colsum_kernel(const float* __restrict__ query,
                              const float* __restrict__ key,
                              const float* __restrict__ w_q,
                              const float* __restrict__ b_q,
                              const float* __restrict__ w_k,
                              float* __restrict__ partial,
                              float* __restrict__ u,
                              int split) {
    const int bid = blockIdx.x;
    const int t   = threadIdx.x;

    if (bid < BSZ) {
        // ---- query path: colsum + two tiny matvecs ----
        __shared__ float qs[HID];
        __shared__ float qsv[HID];
        const int b = bid;
        const float* qbase = query + (size_t)b * LQ * HID;
        float s = 0.f;
        for (int r = 0; r < LQ; ++r) s += qbase[(size_t)r * HID + t];
        qs[t] = s;
        __syncthreads();
        // qsv[o] = dot(w_q[o,:], qs) + Lq * b_q[o]
        const float4* wrow = (const float4*)(w_q + (size_t)t * HID);
        float acc = 0.f;
#pragma unroll 8
        for (int h4 = 0; h4 < HID / 4; ++h4) {
            float4 w = wrow[h4];
            acc += w.x * qs[h4 * 4 + 0] + w.y * qs[h4 * 4 + 1]
                 + w.z * qs[h4 * 4 + 2] + w.w * qs[h4 * 4 + 3];
        }
        qsv[t] = acc + (float)LQ * b_q[t];
        __syncthreads();
        // u[h] = sum_o qsv[o] * w_k[o][h]   (coalesced: t = h)
        float uh = 0.f;
#pragma unroll 4
        for (int o = 0; o < HID; ++o) uh += qsv[o] * w_k[(size_t)o * HID + t];
        u[(size_t)b * HID + t] = uh;
    } else {
        // ---- key path: column sum of a rows-chunk ----
        const int kb    = bid - BSZ;
        const int n     = kb / split;
        const int chunk = kb % split;
        const int rows  = LK / split;
        const float* base = key + (size_t)n * LK * HID + (size_t)chunk * rows * HID;
        const int wave = t >> 6;
        const int lane = t & 63;

        float4 acc0 = make_float4(0.f, 0.f, 0.f, 0.f);
        float4 acc1 = make_float4(0.f, 0.f, 0.f, 0.f);
        const int r0 = wave * (rows / 4);   // contiguous row range per wave
#pragma unroll 4
        for (int i = 0; i < rows / 4; i += 2) {
            float4 v0 = ((const float4*)(base + (size_t)(r0 + i) * HID))[lane];
            float4 v1 = ((const float4*)(base + (size_t)(r0 + i + 1) * HID))[lane];
            acc0.x += v0.x; acc0.y += v0.y; acc0.z += v0.z; acc0.w += v0.w;
            acc1.x += v1.x; acc1.y += v1.y; acc1.z += v1.z; acc1.w += v1.w;
        }
        acc0.x += acc1.x; acc0.y += acc1.y; acc0.z += acc1.z; acc0.w += acc1.w;

        __shared__ float lds[4][HID];
        ((float4*)lds[wave])[lane] = acc0;
        __syncthreads();
        partial[(size_t)kb * HID + t] = lds[0][t] + lds[1][t] + lds[2][t] + lds[3][t];
    }
}

// ---------------------------------------------------------------------------
// Kernel 2: att[b][m] = u[b] . (sum_c partial[(b*M+m)*split + c]); argmax -> idx
// One block per b (8 blocks). First-max tie-break matches jnp.argmax.
// ---------------------------------------------------------------------------
__global__ void argmax_kernel(const float* __restrict__ partial,
                              const float* __restrict__ u,
                              int* __restrict__ idx,
                              int split) {
    const int b    = blockIdx.x;
    const int t    = threadIdx.x;
    const int wave = t >> 6;
    const int lane = t & 63;

    __shared__ float att[M];
    __shared__ float wpart[4];

    const float uv = u[(size_t)b * HID + t];
    for (int m = 0; m < M; ++m) {
        const float* p = partial + ((size_t)(b * M + m) * split) * HID + t;
        float s = 0.f;
        for (int c = 0; c < split; ++c) s += p[(size_t)c * HID];
        float v = uv * s;
        for (int off = 32; off; off >>= 1) v += __shfl_down(v, off);
        if (lane == 0) wpart[wave] = v;
        __syncthreads();
        if (t == 0) att[m] = wpart[0] + wpart[1] + wpart[2] + wpart[3];
        __syncthreads();
    }
    if (t == 0) {
        int best = 0;
        float bv = att[0];
        for (int m = 1; m < M; ++m)
            if (att[m] > bv) { bv = att[m]; best = m; }
        idx[b] = best;
    }
}

// ---------------------------------------------------------------------------
// Kernel 3: out[b][k][h] = key[b*M + idx[b]][k][h]  (float4 copy, 2-D grid)
// ---------------------------------------------------------------------------
__global__ void gather_kernel(const float* __restrict__ key,
                              const int* __restrict__ idx,
                              float* __restrict__ out) {
    const int b = blockIdx.y;
    const size_t per_b = (size_t)LK * HID / 4;  // float4s per batch item: 131072
    const size_t off = (size_t)blockIdx.x * blockDim.x + threadIdx.x;
    const int n = b * M + idx[b];
    ((float4*)out)[(size_t)b * per_b + off] = ((const float4*)key)[(size_t)n * per_b + off];
}

extern "C" void kernel_launch(void* const* d_in, const int* in_sizes, int n_in,
                              void* d_out, int out_size, void* d_ws, size_t ws_size,
                              hipStream_t stream) {
    const float* query = (const float*)d_in[0];
    const float* key   = (const float*)d_in[1];
    const float* w_q   = (const float*)d_in[2];
    const float* b_q   = (const float*)d_in[3];
    const float* w_k   = (const float*)d_in[4];
    float* out = (float*)d_out;

    // split=32 -> 4104 key blocks of 64 KB each (small tail quanta).
    int split = 32;
    while (split > 1) {
        size_t need = sizeof(float) * ((size_t)NKEY * split * HID   // partial
                                       + (size_t)BSZ * HID)         // u
                      + sizeof(int) * BSZ;                          // idx
        if (need <= ws_size) break;
        split >>= 1;
    }

    float* ws = (float*)d_ws;
    size_t off = 0;
    float* partial = ws + off; off += (size_t)NKEY * split * HID;
    float* u       = ws + off; off += (size_t)BSZ * HID;
    int*   idx     = (int*)(ws + off);

    const int nBlocks = BSZ + NKEY * split;
    hipLaunchKernelGGL(colsum_kernel, dim3(nBlocks), dim3(256), 0, stream,
                       query, key, w_q, b_q, w_k, partial, u, split);

    hipLaunchKernelGGL(argmax_kernel, dim3(BSZ), dim3(256), 0, stream,
                       partial, u, idx, split);

    hipLaunchKernelGGL(gather_kernel, dim3(512, BSZ), dim3(256), 0, stream,
                       key, idx, out);
}

// Round 4
// 70.940 us; speedup vs baseline: 2.6830x; 2.6830x over previous
//
#include <hip/hip_runtime.h>

#define HID 256
#define LK  2048
#define LQ  64
#define BSZ 8
#define M   16
#define NKEY (BSZ * M)   // 128

// ---------------------------------------------------------------------------
// Kernel 1:
//  blocks [0, BSZ): per-batch query column-sum + projection to u[b]
//        u[b][h] = sum_o (W_q qs[b] + Lq b_q)[o] * w_k[o][h]
//    (per-thread full loops — slow but correct; these 8 blocks hide under
//     the 4096-block key tail. Do NOT wave-split rows here: waves own
//     disjoint column ranges, so a row-split leaves columns unsummed.)
//  blocks [BSZ, BSZ + NKEY*split): key chunk column sums -> partial[kb][256]
// ---------------------------------------------------------------------------
__global__ void colsum_kernel(const float* __restrict__ query,
                              const float* __restrict__ key,
                              const float* __restrict__ w_q,
                              const float* __restrict__ b_q,
                              const float* __restrict__ w_k,
                              float* __restrict__ partial,
                              float* __restrict__ u,
                              int split) {
    const int bid  = blockIdx.x;
    const int t    = threadIdx.x;
    const int wave = t >> 6;
    const int lane = t & 63;

    if (bid < BSZ) {
        // ---- query path (R1-proven): colsum + two tiny matvecs ----
        __shared__ float qs[HID];
        __shared__ float qsv[HID];
        const int b = bid;
        const float* qbase = query + (size_t)b * LQ * HID;
        float s = 0.f;
        for (int r = 0; r < LQ; ++r) s += qbase[(size_t)r * HID + t];
        qs[t] = s;
        __syncthreads();
        // qsv[o] = dot(w_q[o,:], qs) + Lq * b_q[o]   (o = t)
        const float4* wrow = (const float4*)(w_q + (size_t)t * HID);
        float acc = 0.f;
#pragma unroll 8
        for (int h4 = 0; h4 < HID / 4; ++h4) {
            float4 w = wrow[h4];
            acc += w.x * qs[h4 * 4 + 0] + w.y * qs[h4 * 4 + 1]
                 + w.z * qs[h4 * 4 + 2] + w.w * qs[h4 * 4 + 3];
        }
        qsv[t] = acc + (float)LQ * b_q[t];
        __syncthreads();
        // u[h] = sum_o qsv[o] * w_k[o][h]   (coalesced across t = h)
        float uh = 0.f;
#pragma unroll 4
        for (int o = 0; o < HID; ++o) uh += qsv[o] * w_k[(size_t)o * HID + t];
        u[(size_t)b * HID + t] = uh;
    } else {
        // ---- key path: column sum of a rows-chunk (64 KB contiguous) ----
        const int kb    = bid - BSZ;
        const int n     = kb / split;
        const int chunk = kb % split;
        const int rows  = LK / split;
        const float* base = key + (size_t)n * LK * HID + (size_t)chunk * rows * HID;

        float4 acc0 = make_float4(0.f, 0.f, 0.f, 0.f);
        float4 acc1 = make_float4(0.f, 0.f, 0.f, 0.f);
        const int r0 = wave * (rows / 4);   // contiguous row range per wave
#pragma unroll 4
        for (int i = 0; i < rows / 4; i += 2) {
            float4 v0 = ((const float4*)(base + (size_t)(r0 + i) * HID))[lane];
            float4 v1 = ((const float4*)(base + (size_t)(r0 + i + 1) * HID))[lane];
            acc0.x += v0.x; acc0.y += v0.y; acc0.z += v0.z; acc0.w += v0.w;
            acc1.x += v1.x; acc1.y += v1.y; acc1.z += v1.z; acc1.w += v1.w;
        }
        acc0.x += acc1.x; acc0.y += acc1.y; acc0.z += acc1.z; acc0.w += acc1.w;

        __shared__ float lds[4][HID];
        ((float4*)lds[wave])[lane] = acc0;
        __syncthreads();
        partial[(size_t)kb * HID + t] =
            (lds[0][t] + lds[1][t]) + (lds[2][t] + lds[3][t]);
    }
}

// ---------------------------------------------------------------------------
// Kernel 2: att[n] = u[n/M] . (sum_c partial[n*split + c])
// One block per n = b*M + m (128 blocks, 512 waves -> latency hidden;
// 4 independent accumulator chains for ILP).
// ---------------------------------------------------------------------------
__global__ void att_kernel(const float* __restrict__ partial,
                           const float* __restrict__ u,
                           float* __restrict__ att,
                           int split) {
    const int n    = blockIdx.x;
    const int b    = n / M;
    const int t    = threadIdx.x;
    const int wave = t >> 6;
    const int lane = t & 63;

    const float* p = partial + (size_t)n * split * HID + t;
    float s0 = 0.f, s1 = 0.f, s2 = 0.f, s3 = 0.f;
    int c = 0;
    for (; c + 4 <= split; c += 4) {
        s0 += p[(size_t)(c + 0) * HID];
        s1 += p[(size_t)(c + 1) * HID];
        s2 += p[(size_t)(c + 2) * HID];
        s3 += p[(size_t)(c + 3) * HID];
    }
    for (; c < split; ++c) s0 += p[(size_t)c * HID];

    float v = ((s0 + s1) + (s2 + s3)) * u[(size_t)b * HID + t];
    for (int off = 32; off; off >>= 1) v += __shfl_down(v, off);

    __shared__ float wp[4];
    if (lane == 0) wp[wave] = v;
    __syncthreads();
    if (t == 0) att[n] = (wp[0] + wp[1]) + (wp[2] + wp[3]);
}

// ---------------------------------------------------------------------------
// Kernel 3: argmax over att[b][:] inline, then out[b] = key[b*M + best]
// (float4 copy; the winning key block is likely L3-resident after kernel 1)
// ---------------------------------------------------------------------------
__global__ void gather_kernel(const float* __restrict__ key,
                              const float* __restrict__ att,
                              float* __restrict__ out) {
    const int b = blockIdx.y;
    __shared__ int sidx;
    if (threadIdx.x == 0) {
        const float* a = att + (size_t)b * M;
        int best = 0;
        float bv = a[0];
        for (int m = 1; m < M; ++m) {       // strict > : first-max, matches jnp
            float v = a[m];
            if (v > bv) { bv = v; best = m; }
        }
        sidx = best;
    }
    __syncthreads();
    const int n = b * M + sidx;
    const size_t per_b = (size_t)LK * HID / 4;  // 131072 float4s
    const size_t off = (size_t)blockIdx.x * blockDim.x + threadIdx.x;
    ((float4*)out)[(size_t)b * per_b + off] =
        ((const float4*)key)[(size_t)n * per_b + off];
}

extern "C" void kernel_launch(void* const* d_in, const int* in_sizes, int n_in,
                              void* d_out, int out_size, void* d_ws, size_t ws_size,
                              hipStream_t stream) {
    const float* query = (const float*)d_in[0];
    const float* key   = (const float*)d_in[1];
    const float* w_q   = (const float*)d_in[2];
    const float* b_q   = (const float*)d_in[3];
    const float* w_k   = (const float*)d_in[4];
    float* out = (float*)d_out;

    // split=32 -> 4096 uniform key blocks of 64 KB each (~16 full CU rounds).
    int split = 32;
    while (split > 1) {
        size_t need = sizeof(float) * ((size_t)NKEY * split * HID   // partial
                                       + (size_t)BSZ * HID          // u
                                       + NKEY);                     // att
        if (need <= ws_size) break;
        split >>= 1;
    }

    float* ws = (float*)d_ws;
    size_t off = 0;
    float* partial = ws + off; off += (size_t)NKEY * split * HID;
    float* u       = ws + off; off += (size_t)BSZ * HID;
    float* att     = ws + off; off += NKEY;

    hipLaunchKernelGGL(colsum_kernel, dim3(BSZ + NKEY * split), dim3(256), 0,
                       stream, query, key, w_q, b_q, w_k, partial, u, split);

    hipLaunchKernelGGL(att_kernel, dim3(NKEY), dim3(256), 0, stream,
                       partial, u, att, split);

    hipLaunchKernelGGL(gather_kernel, dim3(512, BSZ), dim3(256), 0, stream,
                       key, att, out);
}

// Round 5
// 69.807 us; speedup vs baseline: 2.7266x; 1.0162x over previous
//
#include <hip/hip_runtime.h>

#define HID 256
#define LK  2048
#define LQ  64
#define BSZ 8
#define M   16
#define NKEY (BSZ * M)   // 128

// ---------------------------------------------------------------------------
// Kernel 1:
//  blocks [0, BSZ): per-batch query column-sum + projection to u[b]
//        u[b][h] = sum_o (W_q qs[b] + Lq b_q)[o] * w_k[o][h]
//    (per-thread full loops — these 8 blocks hide under the 4096-block key
//     tail. Do NOT wave-split rows: waves own disjoint column ranges.)
//    Also zero amax[b] here (runs before att kernel; ws isn't re-poisoned).
//  blocks [BSZ, BSZ + NKEY*split): key chunk column sums -> partial[kb][256]
// ---------------------------------------------------------------------------
__global__ void colsum_kernel(const float* __restrict__ query,
                              const float* __restrict__ key,
                              const float* __restrict__ w_q,
                              const float* __restrict__ b_q,
                              const float* __restrict__ w_k,
                              float* __restrict__ partial,
                              float* __restrict__ u,
                              unsigned long long* __restrict__ amax,
                              int split) {
    const int bid  = blockIdx.x;
    const int t    = threadIdx.x;
    const int wave = t >> 6;
    const int lane = t & 63;

    if (bid < BSZ) {
        // ---- query path: colsum + two tiny matvecs ----
        if (t == 0) amax[bid] = 0ull;   // packed-max init for this call
        __shared__ float qs[HID];
        __shared__ float qsv[HID];
        const int b = bid;
        const float* qbase = query + (size_t)b * LQ * HID;
        float s = 0.f;
        for (int r = 0; r < LQ; ++r) s += qbase[(size_t)r * HID + t];
        qs[t] = s;
        __syncthreads();
        // qsv[o] = dot(w_q[o,:], qs) + Lq * b_q[o]   (o = t)
        const float4* wrow = (const float4*)(w_q + (size_t)t * HID);
        float acc = 0.f;
#pragma unroll 8
        for (int h4 = 0; h4 < HID / 4; ++h4) {
            float4 w = wrow[h4];
            acc += w.x * qs[h4 * 4 + 0] + w.y * qs[h4 * 4 + 1]
                 + w.z * qs[h4 * 4 + 2] + w.w * qs[h4 * 4 + 3];
        }
        qsv[t] = acc + (float)LQ * b_q[t];
        __syncthreads();
        // u[h] = sum_o qsv[o] * w_k[o][h]   (coalesced across t = h)
        float uh = 0.f;
#pragma unroll 4
        for (int o = 0; o < HID; ++o) uh += qsv[o] * w_k[(size_t)o * HID + t];
        u[(size_t)b * HID + t] = uh;
    } else {
        // ---- key path: column sum of a rows-chunk (contiguous) ----
        const int kb    = bid - BSZ;
        const int n     = kb / split;
        const int chunk = kb % split;
        const int rows  = LK / split;
        const float* base = key + (size_t)n * LK * HID + (size_t)chunk * rows * HID;

        // wave w owns contiguous rows [w*rpw, (w+1)*rpw); 4 acc chains,
        // up to 16 float4 loads in flight per thread.
        const int rpw = rows / 4;
        const int r0  = wave * rpw;
        float4 a0 = make_float4(0.f, 0.f, 0.f, 0.f);
        float4 a1 = make_float4(0.f, 0.f, 0.f, 0.f);
        float4 a2 = make_float4(0.f, 0.f, 0.f, 0.f);
        float4 a3 = make_float4(0.f, 0.f, 0.f, 0.f);
#pragma unroll 4
        for (int i = 0; i < rpw; i += 4) {
            float4 v0 = ((const float4*)(base + (size_t)(r0 + i + 0) * HID))[lane];
            float4 v1 = ((const float4*)(base + (size_t)(r0 + i + 1) * HID))[lane];
            float4 v2 = ((const float4*)(base + (size_t)(r0 + i + 2) * HID))[lane];
            float4 v3 = ((const float4*)(base + (size_t)(r0 + i + 3) * HID))[lane];
            a0.x += v0.x; a0.y += v0.y; a0.z += v0.z; a0.w += v0.w;
            a1.x += v1.x; a1.y += v1.y; a1.z += v1.z; a1.w += v1.w;
            a2.x += v2.x; a2.y += v2.y; a2.z += v2.z; a2.w += v2.w;
            a3.x += v3.x; a3.y += v3.y; a3.z += v3.z; a3.w += v3.w;
        }
        a0.x = (a0.x + a1.x) + (a2.x + a3.x);
        a0.y = (a0.y + a1.y) + (a2.y + a3.y);
        a0.z = (a0.z + a1.z) + (a2.z + a3.z);
        a0.w = (a0.w + a1.w) + (a2.w + a3.w);

        __shared__ float lds[4][HID];
        ((float4*)lds[wave])[lane] = a0;
        __syncthreads();
        partial[(size_t)kb * HID + t] =
            (lds[0][t] + lds[1][t]) + (lds[2][t] + lds[3][t]);
    }
}

// ---------------------------------------------------------------------------
// Kernel 2: att = u[n/M] . (sum_c partial[n*split + c]) for n = blockIdx.x;
// then packed atomicMax into amax[b]: high 32 = monotone(float), low 32 =
// (M-1-m) so ties pick the smallest m (jnp.argmax first-max). Max is
// commutative -> deterministic across replays.
// ---------------------------------------------------------------------------
__global__ void att_kernel(const float* __restrict__ partial,
                           const float* __restrict__ u,
                           unsigned long long* __restrict__ amax,
                           int split) {
    const int n    = blockIdx.x;
    const int b    = n / M;
    const int m    = n % M;
    const int t    = threadIdx.x;
    const int wave = t >> 6;
    const int lane = t & 63;

    const float* p = partial + (size_t)n * split * HID + t;
    float s0 = 0.f, s1 = 0.f, s2 = 0.f, s3 = 0.f;
    int c = 0;
    for (; c + 4 <= split; c += 4) {
        s0 += p[(size_t)(c + 0) * HID];
        s1 += p[(size_t)(c + 1) * HID];
        s2 += p[(size_t)(c + 2) * HID];
        s3 += p[(size_t)(c + 3) * HID];
    }
    for (; c < split; ++c) s0 += p[(size_t)c * HID];

    float v = ((s0 + s1) + (s2 + s3)) * u[(size_t)b * HID + t];
    for (int off = 32; off; off >>= 1) v += __shfl_down(v, off);

    __shared__ float wp[4];
    if (lane == 0) wp[wave] = v;
    __syncthreads();
    if (t == 0) {
        float att = (wp[0] + wp[1]) + (wp[2] + wp[3]);
        unsigned int fb = __float_as_uint(att);
        unsigned int mono = (fb & 0x80000000u) ? ~fb : (fb | 0x80000000u);
        unsigned long long pack =
            ((unsigned long long)mono << 32) | (unsigned int)(M - 1 - m);
        atomicMax(&amax[b], pack);
    }
}

// ---------------------------------------------------------------------------
// Kernel 3: decode winner from amax[b] (one broadcast load), float4 copy.
// ---------------------------------------------------------------------------
__global__ void gather_kernel(const float* __restrict__ key,
                              const unsigned long long* __restrict__ amax,
                              float* __restrict__ out) {
    const int b = blockIdx.y;
    const unsigned long long v = amax[b];          // same-address broadcast
    const int m = M - 1 - (int)(v & 0xFFFFFFFFu);
    const int n = b * M + m;
    const size_t per_b = (size_t)LK * HID / 4;     // 131072 float4s
    const size_t off = (size_t)blockIdx.x * blockDim.x + threadIdx.x;
    ((float4*)out)[(size_t)b * per_b + off] =
        ((const float4*)key)[(size_t)n * per_b + off];
}

extern "C" void kernel_launch(void* const* d_in, const int* in_sizes, int n_in,
                              void* d_out, int out_size, void* d_ws, size_t ws_size,
                              hipStream_t stream) {
    const float* query = (const float*)d_in[0];
    const float* key   = (const float*)d_in[1];
    const float* w_q   = (const float*)d_in[2];
    const float* b_q   = (const float*)d_in[3];
    const float* w_k   = (const float*)d_in[4];
    float* out = (float*)d_out;

    // split=32 -> 4096 uniform key blocks of 64 KB each (~16 full CU rounds).
    int split = 32;
    while (split > 1) {
        size_t need = sizeof(unsigned long long) * BSZ                // amax
                      + sizeof(float) * ((size_t)NKEY * split * HID   // partial
                                         + (size_t)BSZ * HID);        // u
        if (need <= ws_size) break;
        split >>= 1;
    }

    // amax first for 8-byte alignment.
    unsigned long long* amax = (unsigned long long*)d_ws;
    float* partial = (float*)(amax + BSZ);
    float* u       = partial + (size_t)NKEY * split * HID;

    hipLaunchKernelGGL(colsum_kernel, dim3(BSZ + NKEY * split), dim3(256), 0,
                       stream, query, key, w_q, b_q, w_k, partial, u, amax, split);

    hipLaunchKernelGGL(att_kernel, dim3(NKEY), dim3(256), 0, stream,
                       partial, u, amax, split);

    hipLaunchKernelGGL(gather_kernel, dim3(512, BSZ), dim3(256), 0, stream,
                       key, amax, out);
}